// Round 8
// baseline (699.482 us; speedup 1.0000x reference)
//
#include <hip/hip_runtime.h>
#include <hip/hip_bf16.h>
#include <math.h>

#define NN 8192
#define DD 512
#define INV_T 14.285714285714286f   // 1/0.07 ; also the logits_max (diagonal) value

typedef __attribute__((ext_vector_type(8))) short s16x8;  // 8 bf16 = 4 VGPRs
typedef __attribute__((ext_vector_type(4))) float f32x4;

__device__ __forceinline__ unsigned short f32_to_bf16(float f) {
  unsigned int u = __float_as_uint(f);
  u += 0x7FFFu + ((u >> 16) & 1u);   // round-to-nearest-even
  return (unsigned short)(u >> 16);
}

__device__ __forceinline__ void async16(const void* g, void* l) {
  // 16B-wide global->LDS DMA; LDS dest must be wave-uniform base + lane*16
  __builtin_amdgcn_global_load_lds((__attribute__((address_space(1))) void*)(void*)g,
                                   (__attribute__((address_space(3))) void*)l,
                                   16, 0, 0);
}

// ---------------- Kernel A: prep = normalize + mask bit-pack + acc zero ----
// (UNCHANGED from R7 — clean baseline for the R8 delta measurement.)
__global__ __launch_bounds__(256) void prep_kernel(const float* __restrict__ f,
                                                   const int* __restrict__ posm,
                                                   const int* __restrict__ negm,
                                                   unsigned short* __restrict__ fnb,
                                                   unsigned long long* __restrict__ pkp,
                                                   unsigned long long* __restrict__ pkn,
                                                   float* __restrict__ acc) {
  // fold the 96KB accumulator memset in: 96 blocks x 256 floats
  if (blockIdx.x < 96) acc[blockIdx.x * 256 + threadIdx.x] = 0.f;

  const int wave = threadIdx.x >> 6;
  const int lane = threadIdx.x & 63;
  const int row  = blockIdx.x * 4 + wave;

  // --- normalize row -> bf16 ---
  const float* src = f + (size_t)row * DD + lane * 8;
  float4 v0 = *(const float4*)src;
  float4 v1 = *(const float4*)(src + 4);
  float ss = v0.x*v0.x + v0.y*v0.y + v0.z*v0.z + v0.w*v0.w
           + v1.x*v1.x + v1.y*v1.y + v1.z*v1.z + v1.w*v1.w;
  #pragma unroll
  for (int o = 32; o; o >>= 1) ss += __shfl_xor(ss, o);
  const float r = 1.0f / fmaxf(sqrtf(ss), 1e-8f);
  ushort4 a, b;
  a.x = f32_to_bf16(v0.x * r); a.y = f32_to_bf16(v0.y * r);
  a.z = f32_to_bf16(v0.z * r); a.w = f32_to_bf16(v0.w * r);
  b.x = f32_to_bf16(v1.x * r); b.y = f32_to_bf16(v1.y * r);
  b.z = f32_to_bf16(v1.z * r); b.w = f32_to_bf16(v1.w * r);
  unsigned short* dst = fnb + (size_t)row * DD + lane * 8;
  *(ushort4*)dst = a;
  *(ushort4*)(dst + 4) = b;

  // --- pack mask rows: bit l of pk*[row*128+w] = (mask[row][64w+l] != 0) ---
  const int* __restrict__ prow = posm + (size_t)row * NN;
  const int* __restrict__ nrow = negm + (size_t)row * NN;
  #pragma unroll 2
  for (int w = 0; w < 128; w += 4) {
    unsigned long long pb[4], nb[4];
    int pv[4], nv[4];
    #pragma unroll
    for (int u = 0; u < 4; ++u) {
      pv[u] = __builtin_nontemporal_load(prow + (w + u) * 64 + lane);
      nv[u] = __builtin_nontemporal_load(nrow + (w + u) * 64 + lane);
    }
    #pragma unroll
    for (int u = 0; u < 4; ++u) {
      pb[u] = __ballot(pv[u] != 0);
      nb[u] = __ballot(nv[u] != 0);
    }
    // ballots are wave-uniform; lanes 0..3 store pb, lanes 4..7 store nb
    unsigned long long rp = pb[0], rn = nb[0];
    rp = ((lane & 3) == 1) ? pb[1] : rp;  rn = ((lane & 3) == 1) ? nb[1] : rn;
    rp = ((lane & 3) == 2) ? pb[2] : rp;  rn = ((lane & 3) == 2) ? nb[2] : rn;
    rp = ((lane & 3) == 3) ? pb[3] : rp;  rn = ((lane & 3) == 3) ? nb[3] : rn;
    if (lane < 4)               pkp[(size_t)row * 128 + w + lane]       = rp;
    else if (lane < 8)          pkn[(size_t)row * 128 + w + (lane - 4)] = rn;
  }
}

// ---------------- Kernel B: fused GEMM + bit-mask epilogue ----------------
// R8: BK 32 -> 64. R7 attribution: the bare 2-barrier BK=32 loop was the
// dominant cost (~90-130us, ~300 TF) — 16 iters x (staging vmcnt(0) drain +
// 2 barriers) around only ~80cy of MFMA each. BK=64 halves the barrier
// pairs and doubles MFMA per phase (2 kslices x 16). LDS 47KB -> 3 blk/CU.
// 8-chunk XOR swizzle (csrc = p ^ (L&7)) derived for 128B rows: within each
// 16-lane ds_read_b128 phase, chunk = (ks*4+q)^(row&7) spreads 16 rows over
// 8 bank-quads -> 2-way (free, m136). Source-side pre-swizzle, linear LDS
// dest (global_load_lds constraint).
__global__ __launch_bounds__(256, 3) void fused_kernel(const unsigned short* __restrict__ fnb,
                                                       const unsigned long long* __restrict__ pkp,
                                                       const unsigned long long* __restrict__ pkn,
                                                       float* __restrict__ Spos,
                                                       float* __restrict__ Sneg,
                                                       float* __restrict__ Pcnt) {
  // decode compact triangular block id -> (bi, bj), bi <= bj, 64x64 block grid
  const int bid = blockIdx.x;
  int bi = (int)(64.5 - sqrt(64.5 * 64.5 - 2.0 * (double)bid));
  while (64 * bi - bi * (bi - 1) / 2 > bid) --bi;
  while (64 * (bi + 1) - (bi + 1) * bi / 2 <= bid) ++bi;
  const int bj = bi + (bid - (64 * bi - bi * (bi - 1) / 2));
  const int I = bi * 128;
  const int J = bj * 128;
  const bool offdiag = (bi != bj);

  const int tid  = threadIdx.x;
  const int wave = tid >> 6;
  const int lane = tid & 63;
  const int wm = wave >> 1;            // 0..1 row half
  const int wn = wave & 1;             // 0..1 col half
  const int q   = lane >> 4;           // 0..3
  const int c16 = lane & 15;           // 0..15

  __shared__ alignas(16) unsigned short lA[128 * 64];   // 16 KB
  __shared__ alignas(16) unsigned short lB[128 * 64];   // 16 KB
  __shared__ float sacc[2][128][3];    // [panel][row][Spos,Sneg,Pcnt]
  // packed mask bits: [kind][row][2 ull + pad]; kind 0=posD 1=negD 2=posT 3=negT
  __shared__ unsigned long long pk[4][128][3];
  for (int t = tid; t < 2 * 128 * 3; t += 256) ((float*)sacc)[t] = 0.f;

  // load this block's mask bits: 512 (kind,row) pairs, 16B each, 2/thread.
  #pragma unroll
  for (int p = 0; p < 2; ++p) {
    const int idx  = tid + p * 256;      // 0..511
    const int kind = idx >> 7;
    const int row  = idx & 127;
    const int rb   = (kind & 2) ? J : I;
    const int cb6  = (kind & 2) ? (I >> 6) : (J >> 6);
    const unsigned long long* __restrict__ m = (kind & 1) ? pkn : pkp;
    const ulonglong2 v = *(const ulonglong2*)(m + (size_t)(rb + row) * 128 + cb6);
    pk[kind][row][0] = v.x;
    pk[kind][row][1] = v.y;
  }

  // ---- GEMM (BK=64, 8 iterations, 2 kslices per iteration) ----
  f32x4 acc[4][4];
  const f32x4 z4 = {0.f, 0.f, 0.f, 0.f};
  #pragma unroll
  for (int mt = 0; mt < 4; ++mt)
    #pragma unroll
    for (int nt = 0; nt < 4; ++nt) acc[mt][nt] = z4;

  for (int kk = 0; kk < DD / 64; ++kk) {
    const int k0 = kk * 64;
    #pragma unroll
    for (int c = 0; c < 4; ++c) {
      const int fidx = tid + c * 256;        // 0..1023 16B-chunks
      const int L    = fidx >> 3;            // LDS row 0..127
      const int p    = fidx & 7;             // physical chunk in 128B row
      const int csrc = p ^ (L & 7);          // 8-chunk XOR swizzle (self-inverse)
      // lA: natural row order
      async16(fnb + (size_t)(I + L) * DD + k0 + csrc * 8, (char*)lA + fidx * 16);
      // lB: row-permuted so epilogue lane c16 owns sim cols 4*c16..4*c16+3
      const int gB = 4 * (L & 31) + (L >> 5);        // inverse of L(brow)
      async16(fnb + (size_t)(J + gB) * DD + k0 + csrc * 8, (char*)lB + fidx * 16);
    }
    __syncthreads();

    #pragma unroll
    for (int ks = 0; ks < 2; ++ks) {
      s16x8 aF[4], bF[4];
      #pragma unroll
      for (int t = 0; t < 4; ++t) {
        const int arow = wm * 64 + t * 16 + c16;
        const int apos = ((ks * 4 + q) ^ (arow & 7)) & 7;
        aF[t] = *(const s16x8*)((const char*)lA + arow * 128 + apos * 16);
        // want global row brow = wn*64 + 4*c16 + t  ->  LDS row L(brow)
        const int Lb = (wn * 16 + c16) | (t << 5);
        const int bpos = ((ks * 4 + q) ^ (Lb & 7)) & 7;
        bF[t] = *(const s16x8*)((const char*)lB + Lb * 128 + bpos * 16);
      }
      #pragma unroll
      for (int mt = 0; mt < 4; ++mt)
        #pragma unroll
        for (int nt = 0; nt < 4; ++nt)
          acc[mt][nt] = __builtin_amdgcn_mfma_f32_16x16x32_bf16(aF[mt], bF[nt], acc[mt][nt], 0, 0, 0);
    }
    __syncthreads();
  }

  // ---- epilogue: pure LDS/VALU, no global loads ----
  // acc[mt][nt][r] = sim[I + wm*64 + mt*16 + q*4 + r][J + wn*64 + 4*c16 + nt]
  #pragma unroll
  for (int mt = 0; mt < 4; ++mt)
    #pragma unroll
    for (int nt = 0; nt < 4; ++nt)
      #pragma unroll
      for (int r = 0; r < 4; ++r)
        acc[mt][nt][r] = __expf(acc[mt][nt][r] * INV_T - INV_T);

  const bool hasdiag = (bi == bj) && (wm == wn);
  const int cb = wn * 64 + 4 * c16;            // local col base
  const int half = c16 >> 3;                   // which 32b half of the 64b word
  const int bsh  = 4 * (c16 & 7);              // bit base within the half

  // direct pass: rows I.., cols J..
  #pragma unroll
  for (int mt = 0; mt < 4; ++mt) {
    const int rl = wm * 64 + mt * 16 + q * 4;  // local row base
    #pragma unroll
    for (int r = 0; r < 4; ++r) {
      const int row = rl + r;
      const uint2 pw = *(const uint2*)&pk[0][row][wn];
      const uint2 nw = *(const uint2*)&pk[1][row][wn];
      const unsigned int p32 = half ? pw.y : pw.x;
      const unsigned int n32 = half ? nw.y : nw.x;
      float dsp = 0.f, dsn = 0.f, dpc = 0.f;
      #pragma unroll
      for (int nt = 0; nt < 4; ++nt) {
        float pf = (float)((p32 >> (bsh + nt)) & 1u);
        float nf = (float)((n32 >> (bsh + nt)) & 1u);
        if (hasdiag && (row == cb + nt)) { pf = 0.f; nf = 0.f; }  // self-contrast diag
        const float e = acc[mt][nt][r];
        dsp = fmaf(e, pf, dsp);
        dsn = fmaf(e, nf, dsn);
        dpc += pf;
      }
      #pragma unroll
      for (int o = 1; o <= 8; o <<= 1) {
        dsp += __shfl_xor(dsp, o);
        dsn += __shfl_xor(dsn, o);
        dpc += __shfl_xor(dpc, o);
      }
      if (c16 == 0) {   // LDS atomics: lgkmcnt only
        atomicAdd(&sacc[0][row][0], dsp);
        atomicAdd(&sacc[0][row][1], dsn);
        atomicAdd(&sacc[0][row][2], dpc);
      }
    }
  }

  // transposed pass: sim(col,row) == sim(row,col); rows J.., cols I..
  if (offdiag) {
    #pragma unroll
    for (int nt = 0; nt < 4; ++nt) {
      const int trl = cb + nt;                 // local row in J-panel
      const uint2 pw = *(const uint2*)&pk[2][trl][wm];
      const uint2 nw = *(const uint2*)&pk[3][trl][wm];
      float ts = 0.f, tn = 0.f, tp = 0.f;
      #pragma unroll
      for (int mt = 0; mt < 4; ++mt) {
        const unsigned int p32 = (mt < 2) ? pw.x : pw.y;
        const unsigned int n32 = (mt < 2) ? nw.x : nw.y;
        #pragma unroll
        for (int r = 0; r < 4; ++r) {
          const int bit = (mt & 1) * 16 + q * 4 + r;
          const float pf = (float)((p32 >> bit) & 1u);
          const float nf = (float)((n32 >> bit) & 1u);
          const float e = acc[mt][nt][r];
          ts = fmaf(e, pf, ts);
          tn = fmaf(e, nf, tn);
          tp += pf;
        }
      }
      ts += __shfl_xor(ts, 16); ts += __shfl_xor(ts, 32);
      tn += __shfl_xor(tn, 16); tn += __shfl_xor(tn, 32);
      tp += __shfl_xor(tp, 16); tp += __shfl_xor(tp, 32);
      if (q == 0) {
        atomicAdd(&sacc[1][trl][0], ts);
        atomicAdd(&sacc[1][trl][1], tn);
        atomicAdd(&sacc[1][trl][2], tp);
      }
    }
  }

  __syncthreads();

  // one batch of global atomics at the very end; nothing waits on them
  const int r = tid & 127;
  if (tid < 128) {
    atomicAdd(&Spos[I + r], sacc[0][r][0]);
    atomicAdd(&Sneg[I + r], sacc[0][r][1]);
    atomicAdd(&Pcnt[I + r], sacc[0][r][2]);
  } else if (offdiag) {
    atomicAdd(&Spos[J + r], sacc[1][r][0]);
    atomicAdd(&Sneg[J + r], sacc[1][r][1]);
    atomicAdd(&Pcnt[J + r], sacc[1][r][2]);
  }
}

// ---------------- Kernel C: finalize ----------------
__global__ __launch_bounds__(256) void finalize_kernel(const float* __restrict__ Spos,
                                                       const float* __restrict__ Sneg,
                                                       const float* __restrict__ Pcnt,
                                                       float* __restrict__ out) {
  float local = 0.f;
  for (int i = threadIdx.x; i < NN; i += 256) {
    const float sp = Spos[i], sn = Sneg[i], pc = Pcnt[i];
    const float card = (pc == 0.f) ? 1.f : pc;
    local += (logf(sn) * pc - sp) / card;
  }
  #pragma unroll
  for (int o = 32; o; o >>= 1) local += __shfl_xor(local, o);
  __shared__ float red[4];
  if ((threadIdx.x & 63) == 0) red[threadIdx.x >> 6] = local;
  __syncthreads();
  if (threadIdx.x == 0)
    out[0] = (red[0] + red[1] + red[2] + red[3]) * (1.0f / (float)NN);
}

extern "C" void kernel_launch(void* const* d_in, const int* in_sizes, int n_in,
                              void* d_out, int out_size, void* d_ws, size_t ws_size,
                              hipStream_t stream) {
  const float* feat = (const float*)d_in[0];
  const int* posm   = (const int*)d_in[1];
  const int* negm   = (const int*)d_in[2];
  float* out = (float*)d_out;

  char* ws = (char*)d_ws;
  unsigned short* fnb      = (unsigned short*)ws;                               // 8 MB
  unsigned long long* pkp  = (unsigned long long*)(ws + (size_t) 8*1024*1024);  // 8 MB
  unsigned long long* pkn  = (unsigned long long*)(ws + (size_t)16*1024*1024);  // 8 MB
  float* Spos = (float*)(ws + (size_t)24 * 1024 * 1024);
  float* Sneg = Spos + NN;
  float* Pcnt = Sneg + NN;
  // DIAGNOSTIC (R8 only): dummy accumulators for the second fused launch.
  float* SposD = (float*)(ws + (size_t)25 * 1024 * 1024);
  float* SnegD = SposD + NN;
  float* PcntD = SnegD + NN;

  prep_kernel<<<NN / 4, 256, 0, stream>>>(feat, posm, negm, fnb, pkp, pkn, Spos);
  fused_kernel<<<2080, 256, 0, stream>>>(fnb, pkp, pkn, Spos, Sneg, Pcnt);
  finalize_kernel<<<1, 256, 0, stream>>>(Spos, Sneg, Pcnt, out);
  // DIAGNOSTIC double-launch: measures fused via dur-delta (and surfaces it
  // in top-5 with counters if >=162us). Outputs go to dummy space; the real
  // result is already computed above. Delete next round.
  fused_kernel<<<2080, 256, 0, stream>>>(fnb, pkp, pkn, SposD, SnegD, PcntD);
}

// Round 9
// 545.022 us; speedup vs baseline: 1.2834x; 1.2834x over previous
//
#include <hip/hip_runtime.h>
#include <hip/hip_bf16.h>
#include <math.h>

#define NN 8192
#define DD 512
#define INV_T 14.285714285714286f   // 1/0.07 ; also the logits_max (diagonal) value

typedef __attribute__((ext_vector_type(8))) short s16x8;  // 8 bf16 = 4 VGPRs
typedef __attribute__((ext_vector_type(4))) float f32x4;
typedef __attribute__((ext_vector_type(4))) int   i32x4;

__device__ __forceinline__ unsigned short f32_to_bf16(float f) {
  unsigned int u = __float_as_uint(f);
  u += 0x7FFFu + ((u >> 16) & 1u);   // round-to-nearest-even
  return (unsigned short)(u >> 16);
}

__device__ __forceinline__ void async16(const void* g, void* l) {
  // 16B-wide global->LDS DMA; LDS dest must be wave-uniform base + lane*16
  __builtin_amdgcn_global_load_lds((__attribute__((address_space(1))) void*)(void*)g,
                                   (__attribute__((address_space(3))) void*)l,
                                   16, 0, 0);
}

// ---------------- Kernel A: normalize rows, emit bf16 (+ zero accumulators) ----
__global__ __launch_bounds__(256) void normalize_kernel(const float* __restrict__ f,
                                                        unsigned short* __restrict__ fnb,
                                                        float* __restrict__ acc) {
  // fold the 96KB accumulator memset in: 96 blocks x 256 floats
  if (blockIdx.x < 96) acc[blockIdx.x * 256 + threadIdx.x] = 0.f;

  const int wave = threadIdx.x >> 6;
  const int lane = threadIdx.x & 63;
  const int row  = blockIdx.x * 4 + wave;
  const float* src = f + (size_t)row * DD + lane * 8;
  float4 v0 = *(const float4*)src;
  float4 v1 = *(const float4*)(src + 4);
  float ss = v0.x*v0.x + v0.y*v0.y + v0.z*v0.z + v0.w*v0.w
           + v1.x*v1.x + v1.y*v1.y + v1.z*v1.z + v1.w*v1.w;
  #pragma unroll
  for (int o = 32; o; o >>= 1) ss += __shfl_xor(ss, o);
  const float r = 1.0f / fmaxf(sqrtf(ss), 1e-8f);
  ushort4 a, b;
  a.x = f32_to_bf16(v0.x * r); a.y = f32_to_bf16(v0.y * r);
  a.z = f32_to_bf16(v0.z * r); a.w = f32_to_bf16(v0.w * r);
  b.x = f32_to_bf16(v1.x * r); b.y = f32_to_bf16(v1.y * r);
  b.z = f32_to_bf16(v1.z * r); b.w = f32_to_bf16(v1.w * r);
  unsigned short* dst = fnb + (size_t)row * DD + lane * 8;
  *(ushort4*)dst = a;
  *(ushort4*)(dst + 4) = b;
}

// ---------------- Kernel B: single fused kernel ----------------
// R9: REVERT to the R0 architecture (best measured: 548.6us) — direct int4
// mask epilogue, no prep/bit-pack (R7/R8 ledger: prep costs ~100us to save
// ~55 -> net loss). The R8 delta-measurement localized the real pig: the
// GEMM K-loop itself (~100us, ~360 TF) — each iteration exposed the staging
// vmcnt(0) drain with ZERO cover (issue -> immediate barrier drain; m233's
// stage+vmcnt+bar=72%). Fix = T3 minimum-2-phase: DOUBLE-BUFFERED LDS,
// next-tile staging issued at the TOP of the iteration, ONE __syncthreads
// per iteration at the END. The barrier's vmcnt(0) now waits on staging
// that had the whole ds_read+MFMA phase (~300cy) to complete -> covered.
// Buffer hazard analysis: iter kk stages buf cur^1 (last READ at iter kk-1;
// those ds_reads completed into regs before iter kk-1's lgkm drain) and
// reads buf cur (staged at kk-1, drained at kk-1's barrier). Safe with one
// barrier. sched_barrier(0) pins stage-issue before the frag reads.
// + XCD swizzle: 2080%8==0 -> (bid&7)*260+(bid>>3) bijective; blocks
// co-resident on an XCD get contiguous triangle ids -> shared A-panels in L2.
__global__ __launch_bounds__(256, 3) void fused_kernel(const unsigned short* __restrict__ fnb,
                                                       const int* __restrict__ posm,
                                                       const int* __restrict__ negm,
                                                       float* __restrict__ Spos,
                                                       float* __restrict__ Sneg,
                                                       float* __restrict__ Pcnt) {
  // XCD-aware swizzle, then decode compact triangular id -> (bi, bj), bi<=bj
  const int bid = (blockIdx.x & 7) * 260 + (blockIdx.x >> 3);   // 2080 = 8*260
  int bi = (int)(64.5 - sqrt(64.5 * 64.5 - 2.0 * (double)bid));
  while (64 * bi - bi * (bi - 1) / 2 > bid) --bi;
  while (64 * (bi + 1) - (bi + 1) * bi / 2 <= bid) ++bi;
  const int bj = bi + (bid - (64 * bi - bi * (bi - 1) / 2));
  const int I = bi * 128;
  const int J = bj * 128;
  const bool offdiag = (bi != bj);

  const int tid  = threadIdx.x;
  const int wave = tid >> 6;
  const int lane = tid & 63;
  const int wm = wave >> 1;            // 0..1 row half
  const int wn = wave & 1;             // 0..1 col half
  const int q   = lane >> 4;           // 0..3
  const int c16 = lane & 15;           // 0..15

  __shared__ alignas(16) unsigned short lA[2][128 * 32];   // double-buffered
  __shared__ alignas(16) unsigned short lB[2][128 * 32];
  __shared__ float sacc[2][128][3];    // [panel][row][Spos,Sneg,Pcnt]
  for (int t = tid; t < 2 * 128 * 3; t += 256) ((float*)sacc)[t] = 0.f;

  // ---- GEMM: dbuf, one barrier per iteration ----
  f32x4 acc[4][4];
  const f32x4 z4 = {0.f, 0.f, 0.f, 0.f};
  #pragma unroll
  for (int mt = 0; mt < 4; ++mt)
    #pragma unroll
    for (int nt = 0; nt < 4; ++nt) acc[mt][nt] = z4;

  // per-thread staging geometry (R0-proven swizzle, 0 conflicts)
  const int fidx0 = tid;          // chunk ids fidx0, fidx0+256
  // prologue: stage tile 0 into buffer 0
  #pragma unroll
  for (int c = 0; c < 2; ++c) {
    const int fidx = tid + c * 256;        // 0..511 16B-chunks
    const int L    = fidx >> 2;            // LDS row 0..127
    const int p    = fidx & 3;
    const int csrc = (p ^ ((L >> 1) & 3)) & 3;     // chunk XOR swizzle
    async16(fnb + (size_t)(I + L) * DD + csrc * 8, (char*)&lA[0][0] + fidx * 16);
    const int gB = 4 * (L & 31) + (L >> 5);        // inverse of L(brow)
    async16(fnb + (size_t)(J + gB) * DD + csrc * 8, (char*)&lB[0][0] + fidx * 16);
  }
  __syncthreads();

  int cur = 0;
  for (int kk = 0; kk < DD / 32; ++kk) {
    // issue NEXT tile's staging first — covered by this tile's reads+MFMA
    if (kk < DD / 32 - 1) {
      const int k0 = (kk + 1) * 32;
      const int nb = cur ^ 1;
      #pragma unroll
      for (int c = 0; c < 2; ++c) {
        const int fidx = fidx0 + c * 256;
        const int L    = fidx >> 2;
        const int p    = fidx & 3;
        const int csrc = (p ^ ((L >> 1) & 3)) & 3;
        async16(fnb + (size_t)(I + L) * DD + k0 + csrc * 8, (char*)&lA[nb][0] + fidx * 16);
        const int gB = 4 * (L & 31) + (L >> 5);
        async16(fnb + (size_t)(J + gB) * DD + k0 + csrc * 8, (char*)&lB[nb][0] + fidx * 16);
      }
    }
    __builtin_amdgcn_sched_barrier(0);   // stage-issue stays before frag reads

    s16x8 aF[4], bF[4];
    #pragma unroll
    for (int t = 0; t < 4; ++t) {
      const int arow = wm * 64 + t * 16 + c16;
      const int apos = (q ^ ((arow >> 1) & 3)) & 3;
      aF[t] = *(const s16x8*)((const char*)&lA[cur][0] + arow * 64 + apos * 16);
      // want global row brow = wn*64 + 4*c16 + t  ->  LDS row L(brow)
      const int Lb = (wn * 16 + c16) | (t << 5);
      const int bpos = (q ^ ((Lb >> 1) & 3)) & 3;
      bF[t] = *(const s16x8*)((const char*)&lB[cur][0] + Lb * 64 + bpos * 16);
    }
    #pragma unroll
    for (int mt = 0; mt < 4; ++mt)
      #pragma unroll
      for (int nt = 0; nt < 4; ++nt)
        acc[mt][nt] = __builtin_amdgcn_mfma_f32_16x16x32_bf16(aF[mt], bF[nt], acc[mt][nt], 0, 0, 0);

    __syncthreads();   // drain covers NEXT tile's staging; protects buffers
    cur ^= 1;
  }

  // ---- epilogue (R0-proven direct mask epilogue) ----
  // acc[mt][nt][r] = sim[I + wm*64 + mt*16 + q*4 + r][J + wn*64 + 4*c16 + nt]
  #pragma unroll
  for (int mt = 0; mt < 4; ++mt)
    #pragma unroll
    for (int nt = 0; nt < 4; ++nt)
      #pragma unroll
      for (int r = 0; r < 4; ++r)
        acc[mt][nt][r] = __expf(acc[mt][nt][r] * INV_T - INV_T);

  const bool hasdiag = (bi == bj) && (wm == wn);
  const int cb = wn * 64 + 4 * c16;            // local col base (this lane's int4)

  // direct pass: rows I.., cols J.. ; 1KB/wave-instr coalesced int4 loads
  #pragma unroll
  for (int mt = 0; mt < 4; ++mt) {
    const int rl = wm * 64 + mt * 16 + q * 4;  // local row base
    i32x4 pv[4], nv[4];
    #pragma unroll
    for (int r = 0; r < 4; ++r) {
      const size_t off = (size_t)(I + rl + r) * NN + J + cb;
      pv[r] = __builtin_nontemporal_load((const i32x4*)(posm + off));
      nv[r] = __builtin_nontemporal_load((const i32x4*)(negm + off));
    }
    #pragma unroll
    for (int r = 0; r < 4; ++r) {
      float dsp = 0.f, dsn = 0.f, dpc = 0.f;
      #pragma unroll
      for (int nt = 0; nt < 4; ++nt) {
        float pf = (float)pv[r][nt];
        float nf = (float)nv[r][nt];
        if (hasdiag && (rl + r == cb + nt)) { pf = 0.f; nf = 0.f; }  // self-contrast diag
        const float e = acc[mt][nt][r];
        dsp = fmaf(e, pf, dsp);
        dsn = fmaf(e, nf, dsn);
        dpc += pf;
      }
      #pragma unroll
      for (int o = 1; o <= 8; o <<= 1) {
        dsp += __shfl_xor(dsp, o);
        dsn += __shfl_xor(dsn, o);
        dpc += __shfl_xor(dpc, o);
      }
      if (c16 == 0) {   // LDS atomics: lgkmcnt only
        atomicAdd(&sacc[0][rl + r][0], dsp);
        atomicAdd(&sacc[0][rl + r][1], dsn);
        atomicAdd(&sacc[0][rl + r][2], dpc);
      }
    }
  }

  // transposed pass: sim(col,row) == sim(row,col); rows J.., cols I..
  if (offdiag) {
    #pragma unroll
    for (int nt = 0; nt < 4; ++nt) {
      const int trl = cb + nt;                 // local row in J-panel
      i32x4 pv[4], nv[4];
      #pragma unroll
      for (int mt = 0; mt < 4; ++mt) {
        const size_t off = (size_t)(J + trl) * NN + I + wm * 64 + mt * 16 + q * 4;
        pv[mt] = __builtin_nontemporal_load((const i32x4*)(posm + off));
        nv[mt] = __builtin_nontemporal_load((const i32x4*)(negm + off));
      }
      float ts = 0.f, tn = 0.f, tp = 0.f;
      #pragma unroll
      for (int mt = 0; mt < 4; ++mt) {
        #pragma unroll
        for (int r = 0; r < 4; ++r) {
          const float e = acc[mt][nt][r];
          ts = fmaf(e, (float)pv[mt][r], ts);
          tn = fmaf(e, (float)nv[mt][r], tn);
          tp += (float)pv[mt][r];
        }
      }
      ts += __shfl_xor(ts, 16); ts += __shfl_xor(ts, 32);
      tn += __shfl_xor(tn, 16); tn += __shfl_xor(tn, 32);
      tp += __shfl_xor(tp, 16); tp += __shfl_xor(tp, 32);
      if (q == 0) {
        atomicAdd(&sacc[1][trl][0], ts);
        atomicAdd(&sacc[1][trl][1], tn);
        atomicAdd(&sacc[1][trl][2], tp);
      }
    }
  }

  __syncthreads();

  // one batch of global atomics at the very end; nothing waits on them
  const int r = tid & 127;
  if (tid < 128) {
    atomicAdd(&Spos[I + r], sacc[0][r][0]);
    atomicAdd(&Sneg[I + r], sacc[0][r][1]);
    atomicAdd(&Pcnt[I + r], sacc[0][r][2]);
  } else if (offdiag) {
    atomicAdd(&Spos[J + r], sacc[1][r][0]);
    atomicAdd(&Sneg[J + r], sacc[1][r][1]);
    atomicAdd(&Pcnt[J + r], sacc[1][r][2]);
  }
}

// ---------------- Kernel C: finalize ----------------
__global__ __launch_bounds__(256) void finalize_kernel(const float* __restrict__ Spos,
                                                       const float* __restrict__ Sneg,
                                                       const float* __restrict__ Pcnt,
                                                       float* __restrict__ out) {
  float local = 0.f;
  for (int i = threadIdx.x; i < NN; i += 256) {
    const float sp = Spos[i], sn = Sneg[i], pc = Pcnt[i];
    const float card = (pc == 0.f) ? 1.f : pc;
    local += (logf(sn) * pc - sp) / card;
  }
  #pragma unroll
  for (int o = 32; o; o >>= 1) local += __shfl_xor(local, o);
  __shared__ float red[4];
  if ((threadIdx.x & 63) == 0) red[threadIdx.x >> 6] = local;
  __syncthreads();
  if (threadIdx.x == 0)
    out[0] = (red[0] + red[1] + red[2] + red[3]) * (1.0f / (float)NN);
}

extern "C" void kernel_launch(void* const* d_in, const int* in_sizes, int n_in,
                              void* d_out, int out_size, void* d_ws, size_t ws_size,
                              hipStream_t stream) {
  const float* feat = (const float*)d_in[0];
  const int* posm   = (const int*)d_in[1];
  const int* negm   = (const int*)d_in[2];
  float* out = (float*)d_out;

  char* ws = (char*)d_ws;
  unsigned short* fnb = (unsigned short*)ws;                 // 8 MB
  float* Spos = (float*)(ws + (size_t)8 * 1024 * 1024);
  float* Sneg = Spos + NN;
  float* Pcnt = Sneg + NN;

  normalize_kernel<<<NN / 4, 256, 0, stream>>>(feat, fnb, Spos);
  fused_kernel<<<2080, 256, 0, stream>>>(fnb, posm, negm, Spos, Sneg, Pcnt);
  finalize_kernel<<<1, 256, 0, stream>>>(Spos, Sneg, Pcnt, out);
}